// Round 1
// baseline (168.942 us; speedup 1.0000x reference)
//
#include <hip/hip_runtime.h>
#include <math.h>

// Shapes (fixed by reference)
#define B_ 4
#define L_ 256
#define H_ 768
#define P_ 32896   // L*(L+1)/2
#define N_ 1536    // 2*H
#define K_ 768
#define M_ 1024    // B*L

// ---------------------------------------------------------------------------
// GEMM: T[m][n] = sum_k A[m][k] * Wsel[n][k]
//   A = seq_hiddens viewed as (B*L, H) row-major
//   Wsel[n][k] = W[n*2H + k]           for n <  H   (U half)
//              = W[(n-H)*2H + H + k]   for n >= H   (V half)
// T layout: (B*L, 2H); first H cols = U, last H cols = V.
// ---------------------------------------------------------------------------
__global__ __launch_bounds__(256) void gemm_uv_kernel(
        const float* __restrict__ A,
        const float* __restrict__ W,
        float* __restrict__ T) {
    constexpr int BM = 64, BN = 64, BK = 16;
    __shared__ float As[BK][BM];
    __shared__ float Bs[BK][BN];

    const int bm = blockIdx.x * BM;
    const int bn = blockIdx.y * BN;
    const int tid = threadIdx.x;

    // Global-load mapping: 4 threads cooperate on one row, float4 along k.
    const int la_m = tid >> 2;          // 0..63
    const int la_k = (tid & 3) * 4;     // 0,4,8,12
    const int n = bn + la_m;            // B tile column (same decomposition)
    const float* wrow = W + ((n < H_) ? (size_t)n * N_
                                      : (size_t)(n - H_) * N_ + H_);
    const float* arow = A + (size_t)(bm + la_m) * K_;

    // Micro-tile mapping: 16x16 threads, 4x4 outputs each.
    const int tm = (tid & 15) * 4;
    const int tn = (tid >> 4) * 4;

    float acc[4][4] = {};

    for (int k0 = 0; k0 < K_; k0 += BK) {
        const float4 av = *(const float4*)(arow + k0 + la_k);
        const float4 bv = *(const float4*)(wrow + k0 + la_k);
        __syncthreads();
        As[la_k + 0][la_m] = av.x;
        As[la_k + 1][la_m] = av.y;
        As[la_k + 2][la_m] = av.z;
        As[la_k + 3][la_m] = av.w;
        Bs[la_k + 0][la_m] = bv.x;
        Bs[la_k + 1][la_m] = bv.y;
        Bs[la_k + 2][la_m] = bv.z;
        Bs[la_k + 3][la_m] = bv.w;
        __syncthreads();
#pragma unroll
        for (int kk = 0; kk < BK; ++kk) {
            const float4 a4 = *(const float4*)(&As[kk][tm]);
            const float4 b4 = *(const float4*)(&Bs[kk][tn]);
            const float a_[4] = {a4.x, a4.y, a4.z, a4.w};
            const float b_[4] = {b4.x, b4.y, b4.z, b4.w};
#pragma unroll
            for (int i = 0; i < 4; ++i)
#pragma unroll
                for (int j = 0; j < 4; ++j)
                    acc[i][j] += a_[i] * b_[j];
        }
    }

#pragma unroll
    for (int i = 0; i < 4; ++i) {
        float4 o = make_float4(acc[i][0], acc[i][1], acc[i][2], acc[i][3]);
        *(float4*)(T + (size_t)(bm + tm + i) * N_ + (bn + tn)) = o;
    }
}

// ---------------------------------------------------------------------------
// Epilogue: out[b, p(i,j), h] = tanh(U[b,i,h] + V[b,j,h] + bias[h])
// Row-tiled: each block owns (b, i, chunk of 16 j's); U row + bias loaded once,
// reused for up to 16 output rows (cuts L2 read traffic ~16x on U/bias).
// p(i,j) = i*(2L+1-i)/2 + (j-i)  [np.triu_indices row-major order]
// ---------------------------------------------------------------------------
__global__ __launch_bounds__(192) void handshake_epilogue_kernel(
        const float* __restrict__ T,
        const float* __restrict__ bias,
        float* __restrict__ out) {
    const int jc = blockIdx.x;   // 0..15  (j chunk)
    const int i  = blockIdx.y;   // 0..255
    const int b  = blockIdx.z;   // 0..3
    const int j0 = jc * 16;
    if (j0 + 15 < i) return;     // whole chunk strictly below diagonal

    const int h = threadIdx.x * 4;   // 192 threads * float4 = 768
    float4 u = *(const float4*)(T + ((size_t)(b * L_ + i) * N_) + h);
    const float4 bs = *(const float4*)(bias + h);
    u.x += bs.x; u.y += bs.y; u.z += bs.z; u.w += bs.w;

    const size_t off_i = (size_t)i * (2 * L_ + 1 - i) / 2;
    const int jlo = (i > j0) ? i : j0;
    const int jhi = j0 + 15;     // always <= 255

    for (int j = jlo; j <= jhi; ++j) {
        const float4 v =
            *(const float4*)(T + ((size_t)(b * L_ + j) * N_) + H_ + h);
        const size_t p = off_i + (size_t)(j - i);
        float4 o;
        o.x = tanhf(u.x + v.x);
        o.y = tanhf(u.y + v.y);
        o.z = tanhf(u.z + v.z);
        o.w = tanhf(u.w + v.w);
        *(float4*)(out + ((size_t)b * P_ + p) * H_ + h) = o;
    }
}

extern "C" void kernel_launch(void* const* d_in, const int* in_sizes, int n_in,
                              void* d_out, int out_size, void* d_ws, size_t ws_size,
                              hipStream_t stream) {
    const float* seq  = (const float*)d_in[0];   // (B, L, H) fp32
    const float* W    = (const float*)d_in[1];   // (H, 2H) fp32
    const float* bias = (const float*)d_in[2];   // (H,) fp32
    float* out = (float*)d_out;                  // (B, P, H) fp32
    float* T   = (float*)d_ws;                   // (B*L, 2H) fp32 = 6.3 MB

    dim3 g1(M_ / 64, N_ / 64);                   // 16 x 24 = 384 blocks
    gemm_uv_kernel<<<g1, 256, 0, stream>>>(seq, W, T);

    dim3 g2(16, L_, B_);                         // (j-chunk, i, b)
    handshake_epilogue_kernel<<<g2, 192, 0, stream>>>(T, bias, out);
}

// Round 2
// 156.551 us; speedup vs baseline: 1.0792x; 1.0792x over previous
//
#include <hip/hip_runtime.h>
#include <math.h>

// Shapes (fixed by reference)
#define B_ 4
#define L_ 256
#define H_ 768
#define P_ 32896   // L*(L+1)/2
#define N_ 1536    // 2*H
#define K_ 768
#define M_ 1024    // B*L

// ---------------------------------------------------------------------------
// GEMM: T[m][n] = sum_k A[m][k] * Wsel[n][k]
//   A = seq_hiddens viewed as (B*L, H) row-major
//   Wsel[n][k] = W[n*2H + k]           for n <  H   (U half)
//              = W[(n-H)*2H + H + k]   for n >= H   (V half)
// T layout: (B*L, 2H); first H cols = U, last H cols = V.
// ---------------------------------------------------------------------------
__global__ __launch_bounds__(256) void gemm_uv_kernel(
        const float* __restrict__ A,
        const float* __restrict__ W,
        float* __restrict__ T) {
    constexpr int BM = 64, BN = 64, BK = 16;
    __shared__ float As[BK][BM];
    __shared__ float Bs[BK][BN];

    const int bm = blockIdx.x * BM;
    const int bn = blockIdx.y * BN;
    const int tid = threadIdx.x;

    // Global-load mapping: 4 threads cooperate on one row, float4 along k.
    const int la_m = tid >> 2;          // 0..63
    const int la_k = (tid & 3) * 4;     // 0,4,8,12
    const int n = bn + la_m;            // B tile column (same decomposition)
    const float* wrow = W + ((n < H_) ? (size_t)n * N_
                                      : (size_t)(n - H_) * N_ + H_);
    const float* arow = A + (size_t)(bm + la_m) * K_;

    // Micro-tile mapping: 16x16 threads, 4x4 outputs each.
    const int tm = (tid & 15) * 4;
    const int tn = (tid >> 4) * 4;

    float acc[4][4] = {};

    for (int k0 = 0; k0 < K_; k0 += BK) {
        const float4 av = *(const float4*)(arow + k0 + la_k);
        const float4 bv = *(const float4*)(wrow + k0 + la_k);
        __syncthreads();
        As[la_k + 0][la_m] = av.x;
        As[la_k + 1][la_m] = av.y;
        As[la_k + 2][la_m] = av.z;
        As[la_k + 3][la_m] = av.w;
        Bs[la_k + 0][la_m] = bv.x;
        Bs[la_k + 1][la_m] = bv.y;
        Bs[la_k + 2][la_m] = bv.z;
        Bs[la_k + 3][la_m] = bv.w;
        __syncthreads();
#pragma unroll
        for (int kk = 0; kk < BK; ++kk) {
            const float4 a4 = *(const float4*)(&As[kk][tm]);
            const float4 b4 = *(const float4*)(&Bs[kk][tn]);
            const float a_[4] = {a4.x, a4.y, a4.z, a4.w};
            const float b_[4] = {b4.x, b4.y, b4.z, b4.w};
#pragma unroll
            for (int i = 0; i < 4; ++i)
#pragma unroll
                for (int j = 0; j < 4; ++j)
                    acc[i][j] += a_[i] * b_[j];
        }
    }

#pragma unroll
    for (int i = 0; i < 4; ++i) {
        float4 o = make_float4(acc[i][0], acc[i][1], acc[i][2], acc[i][3]);
        *(float4*)(T + (size_t)(bm + tm + i) * N_ + (bn + tn)) = o;
    }
}

// ---------------------------------------------------------------------------
// Fast tanh: tanh(x) = 1 - 2/(exp(2x)+1), exp(2x) = exp2(x * 2*log2(e)).
// v_exp_f32 + v_rcp_f32, ~1 ulp each; exact saturation at +-inf:
//   x -> -inf: e=0   -> 1 - 2*rcp(1)   = -1
//   x -> +inf: e=inf -> 1 - 2*rcp(inf) = +1
// 5 VALU ops vs ~25 for libm tanhf.
// ---------------------------------------------------------------------------
__device__ __forceinline__ float fast_tanh(float x) {
    const float e = __builtin_amdgcn_exp2f(x * 2.885390081777926815f);
    const float r = __builtin_amdgcn_rcpf(e + 1.0f);
    return fmaf(-2.0f, r, 1.0f);
}

// ---------------------------------------------------------------------------
// Epilogue: out[b, p(i,j), h] = tanh(U[b,i,h] + V[b,j,h] + bias[h])
// Row-tiled: each block owns (b, i, chunk of 16 j's); U row + bias loaded once,
// reused for up to 16 output rows.
// p(i,j) = i*(2L+1-i)/2 + (j-i)  [np.triu_indices row-major order]
// ---------------------------------------------------------------------------
__global__ __launch_bounds__(192) void handshake_epilogue_kernel(
        const float* __restrict__ T,
        const float* __restrict__ bias,
        float* __restrict__ out) {
    const int jc = blockIdx.x;   // 0..15  (j chunk)
    const int i  = blockIdx.y;   // 0..255
    const int b  = blockIdx.z;   // 0..3
    const int j0 = jc * 16;
    if (j0 + 15 < i) return;     // whole chunk strictly below diagonal

    const int h = threadIdx.x * 4;   // 192 threads * float4 = 768
    float4 u = *(const float4*)(T + ((size_t)(b * L_ + i) * N_) + h);
    const float4 bs = *(const float4*)(bias + h);
    u.x += bs.x; u.y += bs.y; u.z += bs.z; u.w += bs.w;

    const size_t off_i = (size_t)i * (2 * L_ + 1 - i) / 2;
    const int jlo = (i > j0) ? i : j0;
    const int jhi = j0 + 15;     // always <= 255

    for (int j = jlo; j <= jhi; ++j) {
        const float4 v =
            *(const float4*)(T + ((size_t)(b * L_ + j) * N_) + H_ + h);
        const size_t p = off_i + (size_t)(j - i);
        float4 o;
        o.x = fast_tanh(u.x + v.x);
        o.y = fast_tanh(u.y + v.y);
        o.z = fast_tanh(u.z + v.z);
        o.w = fast_tanh(u.w + v.w);
        *(float4*)(out + ((size_t)b * P_ + p) * H_ + h) = o;
    }
}

extern "C" void kernel_launch(void* const* d_in, const int* in_sizes, int n_in,
                              void* d_out, int out_size, void* d_ws, size_t ws_size,
                              hipStream_t stream) {
    const float* seq  = (const float*)d_in[0];   // (B, L, H) fp32
    const float* W    = (const float*)d_in[1];   // (H, 2H) fp32
    const float* bias = (const float*)d_in[2];   // (H,) fp32
    float* out = (float*)d_out;                  // (B, P, H) fp32
    float* T   = (float*)d_ws;                   // (B*L, 2H) fp32 = 6.3 MB

    dim3 g1(M_ / 64, N_ / 64);                   // 16 x 24 = 384 blocks
    gemm_uv_kernel<<<g1, 256, 0, stream>>>(seq, W, T);

    dim3 g2(16, L_, B_);                         // (j-chunk, i, b)
    handshake_epilogue_kernel<<<g2, 192, 0, stream>>>(T, bias, out);
}

// Round 3
// 154.756 us; speedup vs baseline: 1.0917x; 1.0116x over previous
//
#include <hip/hip_runtime.h>
#include <math.h>

// Shapes (fixed by reference)
#define B_ 4
#define L_ 256
#define H_ 768
#define P_ 32896   // L*(L+1)/2
#define N_ 1536    // 2*H
#define K_ 768
#define M_ 1024    // B*L

// ---------------------------------------------------------------------------
// GEMM: T[m][n] = sum_k A[m][k] * Wsel[n][k]
//   A = seq_hiddens viewed as (B*L, H) row-major
//   Wsel[n][k] = W[n*2H + k]           for n <  H   (U half)
//              = W[(n-H)*2H + H + k]   for n >= H   (V half)
// T layout: (B*L, 2H); first H cols = U, last H cols = V.
// BK=32 + register prefetch of next K-chunk to hide global latency.
// ---------------------------------------------------------------------------
__global__ __launch_bounds__(256) void gemm_uv_kernel(
        const float* __restrict__ A,
        const float* __restrict__ W,
        float* __restrict__ T) {
    constexpr int BM = 64, BN = 64, BK = 32;
    __shared__ float As[BK][BM];
    __shared__ float Bs[BK][BN];

    const int bm = blockIdx.x * BM;
    const int bn = blockIdx.y * BN;
    const int tid = threadIdx.x;

    // Global-load mapping: 4 threads per row; each loads 2 float4 chunks.
    const int row = tid >> 2;           // 0..63
    const int q   = tid & 3;            // chunk pair: cols q*4 and q*4+16
    const int c0  = q * 4;
    const int c1  = q * 4 + 16;
    const int n = bn + row;
    const float* wrow = W + ((n < H_) ? (size_t)n * N_
                                      : (size_t)(n - H_) * N_ + H_);
    const float* arow = A + (size_t)(bm + row) * K_;

    // Micro-tile mapping: 16x16 threads, 4x4 outputs each.
    const int tm = (tid & 15) * 4;
    const int tn = (tid >> 4) * 4;

    float acc[4][4] = {};

    // Prefetch first chunk
    float4 a0 = *(const float4*)(arow + c0);
    float4 a1 = *(const float4*)(arow + c1);
    float4 b0 = *(const float4*)(wrow + c0);
    float4 b1 = *(const float4*)(wrow + c1);

    for (int k0 = 0; k0 < K_; k0 += BK) {
        __syncthreads();
        As[c0 + 0][row] = a0.x; As[c0 + 1][row] = a0.y;
        As[c0 + 2][row] = a0.z; As[c0 + 3][row] = a0.w;
        As[c1 + 0][row] = a1.x; As[c1 + 1][row] = a1.y;
        As[c1 + 2][row] = a1.z; As[c1 + 3][row] = a1.w;
        Bs[c0 + 0][row] = b0.x; Bs[c0 + 1][row] = b0.y;
        Bs[c0 + 2][row] = b0.z; Bs[c0 + 3][row] = b0.w;
        Bs[c1 + 0][row] = b1.x; Bs[c1 + 1][row] = b1.y;
        Bs[c1 + 2][row] = b1.z; Bs[c1 + 3][row] = b1.w;
        __syncthreads();

        // Issue next chunk's global loads before compute (latency hidden).
        const int kn = (k0 + BK < K_) ? k0 + BK : k0;
        a0 = *(const float4*)(arow + kn + c0);
        a1 = *(const float4*)(arow + kn + c1);
        b0 = *(const float4*)(wrow + kn + c0);
        b1 = *(const float4*)(wrow + kn + c1);

#pragma unroll
        for (int kk = 0; kk < BK; ++kk) {
            const float4 a4 = *(const float4*)(&As[kk][tm]);
            const float4 b4 = *(const float4*)(&Bs[kk][tn]);
            const float a_[4] = {a4.x, a4.y, a4.z, a4.w};
            const float b_[4] = {b4.x, b4.y, b4.z, b4.w};
#pragma unroll
            for (int i = 0; i < 4; ++i)
#pragma unroll
                for (int j = 0; j < 4; ++j)
                    acc[i][j] += a_[i] * b_[j];
        }
    }

#pragma unroll
    for (int i = 0; i < 4; ++i) {
        float4 o = make_float4(acc[i][0], acc[i][1], acc[i][2], acc[i][3]);
        *(float4*)(T + (size_t)(bm + tm + i) * N_ + (bn + tn)) = o;
    }
}

// ---------------------------------------------------------------------------
// Fast tanh: tanh(x) = 1 - 2/(exp(2x)+1), exp(2x) = exp2(x * 2*log2(e)).
// v_exp_f32 + v_rcp_f32; exact saturation at +-inf. 5 ops vs ~25 for libm.
// ---------------------------------------------------------------------------
__device__ __forceinline__ float fast_tanh(float x) {
    const float e = __builtin_amdgcn_exp2f(x * 2.885390081777926815f);
    const float r = __builtin_amdgcn_rcpf(e + 1.0f);
    return fmaf(-2.0f, r, 1.0f);
}

// ---------------------------------------------------------------------------
// Epilogue: out[b, p(i,j), h] = tanh(U[b,i,h] + V[b,j,h] + bias[h])
// 2D pair-tiled: each block owns (b, 8 i's, 16 j's). 8 bias-added U rows are
// held in registers; each V row is read once per 8 outputs -> read traffic
// drops 5x vs per-(i,j) V reads, leaving the 404 MB write stream dominant.
// p(i,j) = i*(2L+1-i)/2 + (j-i)   [np.triu_indices row-major order]
// ---------------------------------------------------------------------------
__global__ __launch_bounds__(192) void handshake_epilogue_kernel(
        const float* __restrict__ T,
        const float* __restrict__ bias,
        float* __restrict__ out) {
    const int jt = blockIdx.x;          // 0..15  (16 j's each)
    const int it = blockIdx.y;          // 0..31  (8 i's each)
    const int b  = blockIdx.z;          // 0..3
    const int i0 = it * 8;
    const int j0 = jt * 16;
    if (j0 + 15 < i0) return;           // tile entirely below diagonal

    const int h = threadIdx.x * 4;      // 192 threads * float4 = 768
    const float4 bs = *(const float4*)(bias + h);
    const float* Tb = T + (size_t)b * L_ * N_;

    float4 u[8];
#pragma unroll
    for (int ii = 0; ii < 8; ++ii) {
        const float4 t = *(const float4*)(Tb + (size_t)(i0 + ii) * N_ + h);
        u[ii].x = t.x + bs.x; u[ii].y = t.y + bs.y;
        u[ii].z = t.z + bs.z; u[ii].w = t.w + bs.w;
    }

    // Per-row output base: (b*P + off_i - i)*H; add j*H per column.
    size_t rowbase[8];
#pragma unroll
    for (int ii = 0; ii < 8; ++ii) {
        const int i = i0 + ii;
        const size_t off_i = (size_t)i * (2 * L_ + 1 - i) / 2;
        rowbase[ii] = ((size_t)b * P_ + off_i - (size_t)i) * H_;
    }

    for (int jj = 0; jj < 16; ++jj) {
        const int j = j0 + jj;
        const float4 v = *(const float4*)(Tb + (size_t)j * N_ + H_ + h);
        const size_t jH = (size_t)j * H_ + h;
#pragma unroll
        for (int ii = 0; ii < 8; ++ii) {
            const int i = i0 + ii;
            if (i <= j) {
                float4 o;
                o.x = fast_tanh(u[ii].x + v.x);
                o.y = fast_tanh(u[ii].y + v.y);
                o.z = fast_tanh(u[ii].z + v.z);
                o.w = fast_tanh(u[ii].w + v.w);
                *(float4*)(out + rowbase[ii] + jH) = o;
            }
        }
    }
}

extern "C" void kernel_launch(void* const* d_in, const int* in_sizes, int n_in,
                              void* d_out, int out_size, void* d_ws, size_t ws_size,
                              hipStream_t stream) {
    const float* seq  = (const float*)d_in[0];   // (B, L, H) fp32
    const float* W    = (const float*)d_in[1];   // (H, 2H) fp32
    const float* bias = (const float*)d_in[2];   // (H,) fp32
    float* out = (float*)d_out;                  // (B, P, H) fp32
    float* T   = (float*)d_ws;                   // (B*L, 2H) fp32 = 6.3 MB

    dim3 g1(M_ / 64, N_ / 64);                   // 16 x 24 = 384 blocks
    gemm_uv_kernel<<<g1, 256, 0, stream>>>(seq, W, T);

    dim3 g2(16, 32, B_);                         // (j-tile, i-tile, b)
    handshake_epilogue_kernel<<<g2, 192, 0, stream>>>(T, bias, out);
}

// Round 4
// 136.028 us; speedup vs baseline: 1.2420x; 1.1377x over previous
//
#include <hip/hip_runtime.h>
#include <hip/hip_bf16.h>
#include <math.h>

// Shapes (fixed by reference)
#define B_ 4
#define L_ 256
#define H_ 768
#define P_ 32896   // L*(L+1)/2
#define N_ 1536    // 2*H
#define K_ 768
#define M_ 1024    // B*L

typedef __attribute__((ext_vector_type(4))) float f32x4;
typedef __attribute__((ext_vector_type(8))) short s16x8;

__device__ __forceinline__ unsigned pack_bf16(float x, float y) {
    __hip_bfloat16 hx = __float2bfloat16(x);   // RTN
    __hip_bfloat16 hy = __float2bfloat16(y);
    const unsigned short ux = *(const unsigned short*)&hx;
    const unsigned short uy = *(const unsigned short*)&hy;
    return (unsigned)ux | ((unsigned)uy << 16);
}

// ---------------------------------------------------------------------------
// MFMA GEMM: T[m][n] = sum_k A[m][k] * Wsel[n][k]  (+ bias for n < H)
//   A = seq (B*L, H) row-major fp32; Wsel rows are W rows (U half) or
//   k-shifted W rows (V half). Both operands are k-major rows -> feed the
//   16x16x32 bf16 MFMA directly (A: row=l&15, k=(l>>4)*8+j; B: col=l&15).
// Tile 64x64, BK=64, 4 waves in 2x2 of 32x32. LDS XOR-swizzled (chunk ^= row&7)
// so frag ds_read_b128 is 2-way (free) instead of 16-way conflicted.
// ---------------------------------------------------------------------------
__global__ __launch_bounds__(256) void gemm_uv_mfma(
        const float* __restrict__ A, const float* __restrict__ W,
        const float* __restrict__ bias, float* __restrict__ T) {
    __shared__ __align__(16) char As[64 * 128];   // 64 rows x 64 bf16
    __shared__ __align__(16) char Bs[64 * 128];

    const int tid = threadIdx.x;
    const int bm = blockIdx.x * 64;
    const int bn = blockIdx.y * 64;
    const int lane = tid & 63;
    const int wave = tid >> 6;

    // Staging mapping: 16 threads cover one row's 64 k (coalesced 256B runs).
    const int sr = tid >> 4;            // 0..15 (row within 16-row phase)
    const int sk = (tid & 15) * 4;      // 0..60
    const float* wbase = (bn < H_) ? (W + (size_t)bn * N_)
                                   : (W + (size_t)(bn - H_) * N_ + H_);

    const int wm = (wave & 1) * 32;     // wave quadrant
    const int wn = (wave >> 1) * 32;
    const int l15 = lane & 15;
    const int l4  = lane >> 4;

    f32x4 acc[2][2] = {};

    for (int kt = 0; kt < K_; kt += 64) {
        __syncthreads();
#pragma unroll
        for (int ph = 0; ph < 4; ++ph) {
            const int row = ph * 16 + sr;
            const float4 av = *(const float4*)(A + (size_t)(bm + row) * K_ + kt + sk);
            const float4 bv = *(const float4*)(wbase + (size_t)row * N_ + kt + sk);
            const int chunk = sk >> 3;             // 16B chunk 0..7
            const int sub   = (sk & 4) ? 8 : 0;    // low/high half of chunk
            const int boff  = row * 128 + ((chunk ^ (row & 7)) * 16) + sub;
            *(uint2*)(As + boff) = make_uint2(pack_bf16(av.x, av.y), pack_bf16(av.z, av.w));
            *(uint2*)(Bs + boff) = make_uint2(pack_bf16(bv.x, bv.y), pack_bf16(bv.z, bv.w));
        }
        __syncthreads();
#pragma unroll
        for (int ks = 0; ks < 2; ++ks) {
            s16x8 af[2], bf[2];
#pragma unroll
            for (int mi = 0; mi < 2; ++mi) {
                const int row = wm + mi * 16 + l15;
                const int chunk = (ks * 4 + l4) ^ (row & 7);
                af[mi] = *(const s16x8*)(As + row * 128 + chunk * 16);
            }
#pragma unroll
            for (int ni = 0; ni < 2; ++ni) {
                const int row = wn + ni * 16 + l15;
                const int chunk = (ks * 4 + l4) ^ (row & 7);
                bf[ni] = *(const s16x8*)(Bs + row * 128 + chunk * 16);
            }
#pragma unroll
            for (int mi = 0; mi < 2; ++mi)
#pragma unroll
                for (int ni = 0; ni < 2; ++ni)
                    acc[mi][ni] = __builtin_amdgcn_mfma_f32_16x16x32_bf16(
                        af[mi], bf[ni], acc[mi][ni], 0, 0, 0);
        }
    }

    // C-write (fp32), bias folded into U half. D: col=lane&15, row=(lane>>4)*4+r.
#pragma unroll
    for (int mi = 0; mi < 2; ++mi)
#pragma unroll
        for (int ni = 0; ni < 2; ++ni) {
            const int gm0 = bm + wm + mi * 16 + l4 * 4;
            const int gn  = bn + wn + ni * 16 + l15;
            const float badd = (gn < H_) ? bias[gn] : 0.0f;
#pragma unroll
            for (int r = 0; r < 4; ++r)
                T[(size_t)(gm0 + r) * N_ + gn] = acc[mi][ni][r] + badd;
        }
}

// ---------------------------------------------------------------------------
// Fast tanh: tanh(x) = 1 - 2/(exp2(2*log2e*x)+1); exact at +-inf. 5 VALU ops.
// ---------------------------------------------------------------------------
__device__ __forceinline__ float fast_tanh(float x) {
    const float e = __builtin_amdgcn_exp2f(x * 2.885390081777926815f);
    const float r = __builtin_amdgcn_rcpf(e + 1.0f);
    return fmaf(-2.0f, r, 1.0f);
}

// ---------------------------------------------------------------------------
// Epilogue: out[b, p(i,j), h] = tanh(U'[b,i,h] + V[b,j,h])   (U' = U + bias)
// 2D pair-tiled (8 i x 16 j per block); U rows in registers; non-temporal
// output stores keep the 404 MB write stream out of L2 so T stays resident.
// p(i,j) = i*(2L+1-i)/2 + (j-i)
// ---------------------------------------------------------------------------
__global__ __launch_bounds__(192) void handshake_epilogue_kernel(
        const float* __restrict__ T,
        float* __restrict__ out) {
    const int jt = blockIdx.x;          // 0..15
    const int it = blockIdx.y;          // 0..31
    const int b  = blockIdx.z;          // 0..3
    const int i0 = it * 8;
    const int j0 = jt * 16;
    if (j0 + 15 < i0) return;

    const int h = threadIdx.x * 4;      // 192 threads * float4 = 768
    const float* Tb = T + (size_t)b * L_ * N_;

    f32x4 u[8];
#pragma unroll
    for (int ii = 0; ii < 8; ++ii)
        u[ii] = *(const f32x4*)(Tb + (size_t)(i0 + ii) * N_ + h);

    size_t rowbase[8];
#pragma unroll
    for (int ii = 0; ii < 8; ++ii) {
        const int i = i0 + ii;
        const size_t off_i = (size_t)i * (2 * L_ + 1 - i) / 2;
        rowbase[ii] = ((size_t)b * P_ + off_i - (size_t)i) * H_;
    }

    for (int jj = 0; jj < 16; ++jj) {
        const int j = j0 + jj;
        const f32x4 v = *(const f32x4*)(Tb + (size_t)j * N_ + H_ + h);
        const size_t jH = (size_t)j * H_ + h;
#pragma unroll
        for (int ii = 0; ii < 8; ++ii) {
            const int i = i0 + ii;
            if (i <= j) {
                f32x4 o;
                o.x = fast_tanh(u[ii].x + v.x);
                o.y = fast_tanh(u[ii].y + v.y);
                o.z = fast_tanh(u[ii].z + v.z);
                o.w = fast_tanh(u[ii].w + v.w);
                __builtin_nontemporal_store(o, (f32x4*)(out + rowbase[ii] + jH));
            }
        }
    }
}

extern "C" void kernel_launch(void* const* d_in, const int* in_sizes, int n_in,
                              void* d_out, int out_size, void* d_ws, size_t ws_size,
                              hipStream_t stream) {
    const float* seq  = (const float*)d_in[0];   // (B, L, H) fp32
    const float* W    = (const float*)d_in[1];   // (H, 2H) fp32
    const float* bias = (const float*)d_in[2];   // (H,) fp32
    float* out = (float*)d_out;                  // (B, P, H) fp32
    float* T   = (float*)d_ws;                   // (B*L, 2H) fp32 = 6.3 MB

    dim3 g1(M_ / 64, N_ / 64);                   // 16 x 24 = 384 blocks
    gemm_uv_mfma<<<g1, 256, 0, stream>>>(seq, W, bias, T);

    dim3 g2(16, 32, B_);                         // (j-tile, i-tile, b)
    handshake_epilogue_kernel<<<g2, 192, 0, stream>>>(T, out);
}